// Round 7
// baseline (188.637 us; speedup 1.0000x reference)
//
#include <hip/hip_runtime.h>
#include <hip/hip_bf16.h>
#include <cmath>

#define T_DIM 512
#define N_DIM 512
#define M_DIM 256
#define B_DIM 256

typedef __bf16 bf16x8 __attribute__((ext_vector_type(8)));
typedef float  f32x4  __attribute__((ext_vector_type(4)));
typedef unsigned int u32;

#define WAITVM4()  asm volatile("s_waitcnt vmcnt(4) lgkmcnt(0)" ::: "memory")
#define WAITVM0()  asm volatile("s_waitcnt vmcnt(0) lgkmcnt(0)" ::: "memory")
#define PHASE_BARRIER() do { __builtin_amdgcn_sched_barrier(0); \
                             __builtin_amdgcn_s_barrier();      \
                             __builtin_amdgcn_sched_barrier(0); } while (0)

__device__ __forceinline__ void gload16(const __bf16* g, __bf16* l) {
    __builtin_amdgcn_global_load_lds(
        (const __attribute__((address_space(1))) void*)g,
        (__attribute__((address_space(3))) void*)l, 16, 0, 0);
}

// ---------------- precompute: U_e -> bf16 ----------------
__global__ __launch_bounds__(256) void uconv_kernel(
    const float* __restrict__ U, __bf16* __restrict__ Uh)
{
    const int i = (blockIdx.x * 256 + threadIdx.x) * 2;
    float2 v = *(const float2*)(U + i);
    Uh[i]   = (__bf16)v.x;
    Uh[i+1] = (__bf16)v.y;
}

// ---------------- wq[b,t] = concat(h,s) . W_e[t,:] ----------------
__global__ __launch_bounds__(256) void wq_kernel(
    const float* __restrict__ h_t, const float* __restrict__ s_t,
    const float* __restrict__ W_e, float* __restrict__ wq)
{
    __shared__ float q[2 * M_DIM];
    const int b = blockIdx.x;
    const int tid = threadIdx.x;
    q[tid]         = h_t[(size_t)b * M_DIM + tid];
    q[M_DIM + tid] = s_t[(size_t)b * M_DIM + tid];
    __syncthreads();
    for (int tt = tid; tt < T_DIM; tt += 256) {
        const float4* wrow = (const float4*)(W_e + (size_t)tt * (2 * M_DIM));
        float acc = 0.f;
        #pragma unroll 4
        for (int k4 = 0; k4 < (2 * M_DIM) / 4; ++k4) {
            float4 w = wrow[k4];
            acc += q[4*k4+0] * w.x + q[4*k4+1] * w.y
                 + q[4*k4+2] * w.z + q[4*k4+3] * w.w;
        }
        wq[(size_t)b * T_DIM + tt] = acc;
    }
}

// ---------------- fused: in-kernel A-transpose + GEMM + tanh + v-dot ----------------
// Counted-vmcnt schedule (T3+T4): raw s_barrier (no fence -> no auto drain),
// end-of-step s_waitcnt vmcnt(4) retires only the B gloads and leaves the
// 4 pa (A f32 prefetch) HBM loads in flight across the barrier.
__global__ __launch_bounds__(256, 2) void fused5_kernel(
    const float* __restrict__ data, const __bf16* __restrict__ Uh,
    const float* __restrict__ v_e, const float* __restrict__ wq,
    float* __restrict__ partial)
{
    __shared__ __align__(16) __bf16 As[2][128 * 32];   // [n][t], swizzled blocks
    __shared__ __align__(16) __bf16 Bs[2][256 * 32];   // [s][t], linear (gload_lds)
    __shared__ float sc[128];

    // XCD-aware decode: both sh-halves of a (b,nb) pair land on the same XCD.
    const int wg    = blockIdx.x;
    const int xcd   = wg & 7;
    const int local = wg >> 3;
    const int sh    = local & 1;
    const int p     = xcd + 8 * (local >> 1);   // bijective over [0,1024)
    const int b     = p >> 2;
    const int nb    = p & 3;

    const int tid  = threadIdx.x;
    const int lane = tid & 63;
    const int wid  = tid >> 6;
    const int wm   = wid >> 1;           // n-half
    const int wn   = wid & 1;            // s-half

    if (tid < 128) sc[tid] = 0.f;

    f32x4 acc[4][8];
    const f32x4 zero = {0.f, 0.f, 0.f, 0.f};
    #pragma unroll
    for (int i = 0; i < 4; ++i)
        #pragma unroll
        for (int j = 0; j < 8; ++j)
            acc[i][j] = zero;

    const float*  Ab = data + (size_t)b * T_DIM * N_DIM + nb * 128;
    const __bf16* Bb = Uh + (size_t)(sh * 256) * T_DIM;

    // A staging: rp = t-pair row, cg = n col-group; 16 lanes = 512 contiguous bytes.
    const int rp = tid >> 4;
    const int cg = tid & 15;
    const int n0 = cg * 8;
    const int swzk = (cg & 3) << 2;      // XOR key on u32-index bits 2-3

    // B staging: 4 x gload_lds, linear dest
    const int r0 = tid >> 2;
    const int ce = (tid & 3) * 8;

    const int fr = lane & 15;
    const int kb = (lane >> 4) * 8;

    // fragment read offsets (A matches write swizzle)
    int aoff[4];
    #pragma unroll
    for (int mi = 0; mi < 4; ++mi) {
        const int row = wm * 64 + mi * 16 + fr;
        aoff[mi] = (row * 32 + kb) ^ (((row >> 3) & 3) << 3);
    }
    int boff[8];
    #pragma unroll
    for (int ni = 0; ni < 8; ++ni)
        boff[ni] = (wn * 128 + ni * 16 + fr) * 32 + kb;

    // ---- prologue: stage tile 0 into buf 0, prefetch pa for tile 1
    const float* s0 = Ab + (size_t)(2 * rp) * N_DIM + n0;
    float4 pa0 = *(const float4*)s0;
    float4 pa1 = *(const float4*)(s0 + 4);
    float4 pa2 = *(const float4*)(s0 + N_DIM);
    float4 pa3 = *(const float4*)(s0 + N_DIM + 4);

    #pragma unroll
    for (int i = 0; i < 4; ++i)
        gload16(Bb + (size_t)(i * 64 + r0) * T_DIM + ce, &Bs[0][tid * 8] + i * 64 * 32);
    {
        u32* As32 = (u32*)As[0];
        const float lo_[8] = {pa0.x, pa0.y, pa0.z, pa0.w, pa1.x, pa1.y, pa1.z, pa1.w};
        const float hi_[8] = {pa2.x, pa2.y, pa2.z, pa2.w, pa3.x, pa3.y, pa3.z, pa3.w};
        #pragma unroll
        for (int j = 0; j < 8; ++j) {
            __bf16 l = (__bf16)lo_[j];
            __bf16 h = (__bf16)hi_[j];
            u32 w = ((u32)__builtin_bit_cast(unsigned short, h) << 16)
                  |  (u32)__builtin_bit_cast(unsigned short, l);
            As32[((n0 + j) * 16 + rp) ^ swzk] = w;
        }
    }
    {   // pa for tile 1 (stays in flight across the prologue barrier)
        const float* sn = Ab + (size_t)(32 + 2 * rp) * N_DIM + n0;
        pa0 = *(const float4*)sn;
        pa1 = *(const float4*)(sn + 4);
        pa2 = *(const float4*)(sn + N_DIM);
        pa3 = *(const float4*)(sn + N_DIM + 4);
    }
    WAITVM4();          // retire B gloads + own ds_writes; pa(tile1) stays in flight
    PHASE_BARRIER();    // buf0 ready for all waves

    int cur = 0;
    // main loop: 15 staging iterations (k0 = 0..448), last tile peeled
    for (int k0 = 0; k0 < T_DIM - 32; k0 += 32) {
        const int nxt = cur ^ 1;

        // ---- fragment reads from buf[cur] first (longest latency to MFMA)
        bf16x8 a[4], bv[8];
        #pragma unroll
        for (int mi = 0; mi < 4; ++mi)
            a[mi] = *(const bf16x8*)&As[cur][aoff[mi]];
        #pragma unroll
        for (int ni = 0; ni < 8; ++ni)
            bv[ni] = *(const bf16x8*)&Bs[cur][boff[ni]];

        // ---- stage B[k+1] into buf[nxt]
        #pragma unroll
        for (int i = 0; i < 4; ++i)
            gload16(Bb + (size_t)(i * 64 + r0) * T_DIM + (k0 + 32) + ce,
                    &Bs[nxt][tid * 8] + i * 64 * 32);

        // ---- cvt pa (tile k+1) -> swizzled transpose write into As[nxt]
        // (compiler inserts the exact vmcnt for the pa dependency)
        {
            u32* As32 = (u32*)As[nxt];
            const float lo_[8] = {pa0.x, pa0.y, pa0.z, pa0.w, pa1.x, pa1.y, pa1.z, pa1.w};
            const float hi_[8] = {pa2.x, pa2.y, pa2.z, pa2.w, pa3.x, pa3.y, pa3.z, pa3.w};
            #pragma unroll
            for (int j = 0; j < 8; ++j) {
                __bf16 l = (__bf16)lo_[j];
                __bf16 h = (__bf16)hi_[j];
                u32 w = ((u32)__builtin_bit_cast(unsigned short, h) << 16)
                      |  (u32)__builtin_bit_cast(unsigned short, l);
                As32[((n0 + j) * 16 + rp) ^ swzk] = w;
            }
        }

        // ---- issue pa loads for tile k+2 (consumed next iteration)
        const bool more = (k0 + 64 < T_DIM);
        if (more) {
            const float* sn = Ab + (size_t)(k0 + 64 + 2 * rp) * N_DIM + n0;
            pa0 = *(const float4*)sn;
            pa1 = *(const float4*)(sn + 4);
            pa2 = *(const float4*)(sn + N_DIM);
            pa3 = *(const float4*)(sn + N_DIM + 4);
        }

        // ---- MFMA on tile k
        __builtin_amdgcn_s_setprio(1);
        #pragma unroll
        for (int mi = 0; mi < 4; ++mi)
            #pragma unroll
            for (int ni = 0; ni < 8; ++ni)
                acc[mi][ni] = __builtin_amdgcn_mfma_f32_16x16x32_bf16(a[mi], bv[ni], acc[mi][ni], 0, 0, 0);
        __builtin_amdgcn_s_setprio(0);

        // ---- retire B gloads + LDS ops; leave pa[k+2] in flight (if issued)
        if (more) { WAITVM4(); } else { WAITVM0(); }
        PHASE_BARRIER();
        cur = nxt;
    }

    // ---- peeled last tile (no staging)
    {
        bf16x8 a[4], bv[8];
        #pragma unroll
        for (int mi = 0; mi < 4; ++mi)
            a[mi] = *(const bf16x8*)&As[cur][aoff[mi]];
        #pragma unroll
        for (int ni = 0; ni < 8; ++ni)
            bv[ni] = *(const bf16x8*)&Bs[cur][boff[ni]];
        __builtin_amdgcn_s_setprio(1);
        #pragma unroll
        for (int mi = 0; mi < 4; ++mi)
            #pragma unroll
            for (int ni = 0; ni < 8; ++ni)
                acc[mi][ni] = __builtin_amdgcn_mfma_f32_16x16x32_bf16(a[mi], bv[ni], acc[mi][ni], 0, 0, 0);
        __builtin_amdgcn_s_setprio(0);
    }

    // ---- epilogue: tanh + v-weighted reduce over this wave's 128 s-columns
    float wqv[8], vev[8];
    #pragma unroll
    for (int ni = 0; ni < 8; ++ni) {
        const int scol = sh * 256 + wn * 128 + ni * 16 + fr;
        wqv[ni] = wq[(size_t)b * T_DIM + scol];
        vev[ni] = v_e[scol];
    }
    const int g = lane >> 4;
    #pragma unroll
    for (int mi = 0; mi < 4; ++mi) {
        #pragma unroll
        for (int rg = 0; rg < 4; ++rg) {
            float part = 0.f;
            #pragma unroll
            for (int ni = 0; ni < 8; ++ni)
                part += vev[ni] * tanhf(wqv[ni] + acc[mi][ni][rg]);
            part += __shfl_xor(part, 1);
            part += __shfl_xor(part, 2);
            part += __shfl_xor(part, 4);
            part += __shfl_xor(part, 8);
            if (fr == 0)
                atomicAdd(&sc[wm * 64 + mi * 16 + 4 * g + rg], part);
            // exactly 2 adds per slot (wn=0,1): f32 add commutative -> deterministic
        }
    }
    __syncthreads();
    if (tid < 128)
        partial[((size_t)b * 2 + sh) * N_DIM + nb * 128 + tid] = sc[tid];
}

// ---------------- softmax over n (sums the 2 s-half partials) ----------------
__global__ __launch_bounds__(512) void softmax_kernel(
    const float* __restrict__ partial, float* __restrict__ out)
{
    const int b = blockIdx.x;
    const int n = threadIdx.x;
    const float* p = partial + (size_t)b * 2 * N_DIM;
    float s = p[n] + p[N_DIM + n];

    float m = s;
    #pragma unroll
    for (int off = 1; off < 64; off <<= 1)
        m = fmaxf(m, __shfl_xor(m, off));
    __shared__ float red[8];
    const int wv = n >> 6;
    if ((n & 63) == 0) red[wv] = m;
    __syncthreads();
    float bm = red[0];
    #pragma unroll
    for (int i = 1; i < 8; ++i) bm = fmaxf(bm, red[i]);

    float e = expf(s - bm);
    float t = e;
    #pragma unroll
    for (int off = 1; off < 64; off <<= 1)
        t += __shfl_xor(t, off);
    __syncthreads();
    if ((n & 63) == 0) red[wv] = t;
    __syncthreads();
    float tot = 0.f;
    #pragma unroll
    for (int i = 0; i < 8; ++i) tot += red[i];

    out[(size_t)b * N_DIM + n] = e / tot;
}

extern "C" void kernel_launch(void* const* d_in, const int* in_sizes, int n_in,
                              void* d_out, int out_size, void* d_ws, size_t ws_size,
                              hipStream_t stream) {
    const float* h_t  = (const float*)d_in[0];
    const float* s_t  = (const float*)d_in[1];
    const float* data = (const float*)d_in[2];
    const float* W_e  = (const float*)d_in[3];
    const float* U_e  = (const float*)d_in[4];
    const float* v_e  = (const float*)d_in[5];
    float* out = (float*)d_out;

    const size_t wq_elems      = (size_t)B_DIM * T_DIM;         // f32
    const size_t partial_elems = (size_t)B_DIM * 2 * N_DIM;     // f32
    const size_t u_elems       = (size_t)T_DIM * T_DIM;         // bf16

    float* wq      = (float*)d_ws;
    float* partial = wq + wq_elems;
    __bf16* Uh     = (__bf16*)(partial + partial_elems);

    wq_kernel<<<B_DIM, 256, 0, stream>>>(h_t, s_t, W_e, wq);
    uconv_kernel<<<(int)(u_elems / 512), 256, 0, stream>>>(U_e, Uh);
    fused5_kernel<<<B_DIM * 8, 256, 0, stream>>>(data, Uh, v_e, wq, partial);
    softmax_kernel<<<B_DIM, 512, 0, stream>>>(partial, out);
}